// Round 14
// baseline (160.268 us; speedup 1.0000x reference)
//
#include <hip/hip_runtime.h>

typedef __bf16 bf16x8 __attribute__((ext_vector_type(8)));
typedef float f32x4 __attribute__((ext_vector_type(4)));

#define SCALE_F 0.014731391274719738f   /* 1/sqrt(9*512) */
#define SCALE2_F 2.170138888888889e-4f  /* 1/4608 */

__device__ __forceinline__ ushort f2bf(float f) {
    uint x = __float_as_uint(f);
    uint r = (x + 0x7fffu + ((x >> 16) & 1u)) >> 16;
    return (ushort)r;
}

__device__ __forceinline__ void async_cp16(const void* g, void* l) {
    __builtin_amdgcn_global_load_lds(
        (const __attribute__((address_space(1))) void*)g,
        (__attribute__((address_space(3))) void*)l, 16, 0, 0);
}

// ---------------- prep kernels (R13, unchanged) ----------------

__global__ void k_prep(const float* __restrict__ kern, float* __restrict__ Q,
                       const float* __restrict__ x, ushort* __restrict__ xp) {
    int bx = blockIdx.x;
    if (bx < 1024) {
        int idx = bx * 256 + threadIdx.x;
        float s = 0.f;
#pragma unroll
        for (int t = 0; t < 9; ++t) { float v = kern[t * 262144 + idx]; s += v * v; }
        Q[idx] = s * SCALE2_F;
        return;
    }
    int idx = (bx - 1024) * 256 + threadIdx.x;
    int pos = idx >> 6, e = idx & 63;
    int b = pos / 4356, rem = pos - b * 4356;
    int hp = rem / 66, wp = rem - hp * 66;
    int ci0 = e << 3;
    uint4 o = make_uint4(0u, 0u, 0u, 0u);
    if (hp >= 1 && hp <= 64 && wp >= 1 && wp <= 64) {
        const float4* s =
            (const float4*)(x + (((size_t)(b * 4096 + (hp - 1) * 64 + (wp - 1))) << 9) + ci0);
        float4 v0 = s[0], v1 = s[1];
        o.x = (uint)f2bf(v0.x) | ((uint)f2bf(v0.y) << 16);
        o.y = (uint)f2bf(v0.z) | ((uint)f2bf(v0.w) << 16);
        o.z = (uint)f2bf(v1.x) | ((uint)f2bf(v1.y) << 16);
        o.w = (uint)f2bf(v1.z) | ((uint)f2bf(v1.w) << 16);
    }
    *(uint4*)(xp + (((size_t)pos) << 9) + ci0) = o;
}

__global__ void k_sigma(const float* __restrict__ style, const float* __restrict__ Q,
                        float* __restrict__ sig) {
    __shared__ float s2[512];
    int b = blockIdx.x, cq = blockIdx.y;
    int t = threadIdx.x;
    {
        float s0 = style[b * 512 + t];
        float s1 = style[b * 512 + 256 + t];
        s2[t] = s0 * s0;
        s2[256 + t] = s1 * s1;
    }
    __syncthreads();
    int co = cq * 64 + (t & 63);
    int ciq = (t >> 6) * 128;
    float acc = 0.f;
#pragma unroll 16
    for (int ci = 0; ci < 128; ++ci) acc += s2[ciq + ci] * Q[(ciq + ci) * 512 + co];
    __shared__ float part[4][64];
    part[t >> 6][t & 63] = acc;
    __syncthreads();
    if (t < 64) {
        float v = part[0][t] + part[1][t] + part[2][t] + part[3][t];
        sig[b * 512 + cq * 64 + t] = rsqrtf(v + 1e-8f);
    }
}

__global__ void k_wt(const float* __restrict__ kern, const float* __restrict__ style,
                     const float* __restrict__ sig, ushort* __restrict__ wT) {
    __shared__ float tile[64][65];
    int tap = blockIdx.y;
    int ci0 = (blockIdx.x >> 3) << 6, co0 = (blockIdx.x & 7) << 6;
    int t = threadIdx.x;
    int col = t & 63, rq = t >> 6;
#pragma unroll
    for (int r = 0; r < 16; ++r) {
        int ci_l = r * 4 + rq;
        tile[ci_l][col] = SCALE_F * kern[(size_t)(tap * 512 + ci0 + ci_l) * 512 + co0 + col];
    }
    __syncthreads();
#pragma unroll 1
    for (int b = 0; b < 8; ++b) {
#pragma unroll
        for (int r = 0; r < 4; ++r) {
            int q = r * 256 + t;
            int co_l = q >> 4;
            int ciq = (q & 15) << 2;
            float sg = sig[b * 512 + co0 + co_l];
            float v0 = tile[ciq + 0][co_l] * style[b * 512 + ci0 + ciq + 0] * sg;
            float v1 = tile[ciq + 1][co_l] * style[b * 512 + ci0 + ciq + 1] * sg;
            float v2 = tile[ciq + 2][co_l] * style[b * 512 + ci0 + ciq + 2] * sg;
            float v3 = tile[ciq + 3][co_l] * style[b * 512 + ci0 + ciq + 3] * sg;
            uint lo = (uint)f2bf(v0) | ((uint)f2bf(v1) << 16);
            uint hi = (uint)f2bf(v2) | ((uint)f2bf(v3) << 16);
            *(uint2*)(&wT[((size_t)(b * 9 + tap) * 512 + co0 + co_l) * 512 + ci0 + ciq]) =
                make_uint2(lo, hi);
        }
    }
}

// ---------------- main conv: 256x256, BK=64, 8 waves, relaxed-barrier pipeline ----------------
// R14 = R9 read/MFMA stream with barriers halved: s_barrier only at ph0/ph4
// (before stage ISSUE, which moves post-barrier) and ph3/ph7 (vm(4)-attested
// cross-wave stage->read handoff). ph1/2/5/6 use barrier-less counted lgkm
// waits (per-wave data readiness needs no barrier). Waves may skew between
// barriers -> LDS port streams under MFMA instead of lockstep alternation.
// VM ledger/iter: ph0 +8 (12 out), ph3 vm(4)->4, ph4 +8 (12), ph7 vm(4)->4.
__global__ __launch_bounds__(512, 2) void conv_mfma(const ushort* __restrict__ xpad,
                                                    const ushort* __restrict__ wT,
                                                    float* __restrict__ out) {
    extern __shared__ char lds[];

    const int wg = blockIdx.x;                      // 0..255
    const int swz = (wg & 7) * 32 + (wg >> 3);      // bijective XCD swizzle
    const int mt = swz & 15;
    const int nt = (swz >> 4) & 1;
    const int b = swz >> 5;

    const int tid = threadIdx.x;
    const int l = tid & 63, wv = tid >> 6;
    const int wm = (wv >> 2) * 128;
    const int wn = (wv & 3) * 64;
    const int ha = wv >> 2;          // A half this wave reads
    const int hb = (wv & 3) >> 1;    // B half this wave reads

    const int rl = l >> 3;
    const int g = (l & 7) ^ rl;      // data chunk pre-swizzle
    const ushort* baseA[2][2];
    const ushort* baseB[2][2];
#pragma unroll
    for (int h = 0; h < 2; ++h)
#pragma unroll
        for (int i = 0; i < 2; ++i) {
            int rloc = wv * 16 + i * 8 + rl;
            int R = h * 128 + rloc;
            baseA[h][i] = xpad + ((size_t)((b * 66 + mt * 4 + (R >> 6)) * 66 + (R & 63))) * 512 + g * 8;
            baseB[h][i] = wT + ((size_t)(b * 9 * 512 + nt * 256 + R)) * 512 + g * 8;
        }
    const int so0 = (wv * 16) * 128;
    const int so1 = (wv * 16 + 8) * 128;

    auto offA = [](int t) -> int {
        int tap = t >> 3;
        int ky = (tap * 11) >> 5;
        int kx = tap - ky * 3;
        return (ky * 66 + kx) * 512 + ((t & 7) << 6);
    };
    auto offB = [](int t) -> int { return (t >> 3) * 262144 + ((t & 7) << 6); };

    auto stA = [&](int t, int h) {
        int ts = t > 71 ? 71 : t;
        int o = offA(ts);
        char* d = lds + (t & 1) * 32768 + h * 16384;
        async_cp16(baseA[h][0] + o, d + so0);
        async_cp16(baseA[h][1] + o, d + so1);
    };
    auto stB = [&](int t, int h) {
        int ts = t > 71 ? 71 : t;
        int o = offB(ts);
        char* d = lds + 65536 + (t & 1) * 32768 + h * 16384;
        async_cp16(baseB[h][0] + o, d + so0);
        async_cp16(baseB[h][1] + o, d + so1);
    };

    const int frow = l & 15;
    const int fchunk_base = l >> 4;   // 0..3
    const int fxor = l & 7;

    f32x4 acc[8][4];
#pragma unroll
    for (int mi = 0; mi < 8; ++mi)
#pragma unroll
        for (int ni = 0; ni < 4; ++ni) acc[mi][ni] = (f32x4){0.f, 0.f, 0.f, 0.f};

    bf16x8 bq[4][2];             // single bank, refilled post-MFMA at ph3/ph7 tails
    bf16x8 aqE[2][2], aqO[2][2]; // A-frag parity banks (read 1 phase ahead)

    auto rdB = [&](const char* bB) {
#pragma unroll
        for (int kk = 0; kk < 2; ++kk)
#pragma unroll
            for (int ni = 0; ni < 4; ++ni) {
                int r = (wn & 64) + ni * 16 + frow;
                bq[ni][kk] = *(const bf16x8*)(bB + r * 128 +
                                              (((kk * 4 + fchunk_base) ^ fxor) * 16));
            }
    };
    auto rdA = [&](bf16x8 (&aq)[2][2], const char* aB, int q) {
#pragma unroll
        for (int m2 = 0; m2 < 2; ++m2)
#pragma unroll
            for (int kk = 0; kk < 2; ++kk) {
                int r = (2 * q + m2) * 16 + frow;
                aq[m2][kk] = *(const bf16x8*)(aB + r * 128 +
                                              (((kk * 4 + fchunk_base) ^ fxor) * 16));
            }
    };

// barrier fences (ph0/ph4: before stage issue; ph3/ph7: stage->read handoff)
#define FB_L4                                                           \
    {                                                                   \
        __builtin_amdgcn_sched_barrier(0);                              \
        asm volatile("s_waitcnt lgkmcnt(4)" ::: "memory");              \
        __builtin_amdgcn_s_barrier();                                   \
        __builtin_amdgcn_sched_barrier(0);                              \
    }
#define FB_V4L0                                                         \
    {                                                                   \
        __builtin_amdgcn_sched_barrier(0);                              \
        asm volatile("s_waitcnt vmcnt(4) lgkmcnt(0)" ::: "memory");     \
        __builtin_amdgcn_s_barrier();                                   \
        __builtin_amdgcn_sched_barrier(0);                              \
    }
// barrier-less counted wait (per-wave data readiness only)
#define FN_L4                                                           \
    {                                                                   \
        __builtin_amdgcn_sched_barrier(0);                              \
        asm volatile("s_waitcnt lgkmcnt(4)" ::: "memory");              \
        __builtin_amdgcn_sched_barrier(0);                              \
    }

#define MFMA16(Q, AQ)                                                                  \
    do {                                                                               \
        __builtin_amdgcn_s_setprio(1);                                                 \
        _Pragma("unroll") for (int kk = 0; kk < 2; ++kk)                               \
            _Pragma("unroll") for (int ni = 0; ni < 4; ++ni)                           \
                _Pragma("unroll") for (int m2 = 0; m2 < 2; ++m2)                       \
                    acc[2 * (Q) + m2][ni] = __builtin_amdgcn_mfma_f32_16x16x32_bf16(   \
                        (AQ)[m2][kk], bq[ni][kk], acc[2 * (Q) + m2][ni], 0, 0, 0);     \
        __builtin_amdgcn_s_setprio(0);                                                 \
    } while (0)

    const char* Ab0 = lds + ha * 16384;
    const char* Ab1 = lds + 32768 + ha * 16384;
    const char* Bb0 = lds + 65536 + hb * 16384;
    const char* Bb1 = lds + 98304 + hb * 16384;

    // prologue: land A(0),B(0); B(1) in flight (vm=4); pre-read A(0)q0 + B(0)
    stA(0, 0); stA(0, 1);
    stB(0, 0); stB(0, 1);
    asm volatile("s_waitcnt vmcnt(0)" ::: "memory");
    __builtin_amdgcn_sched_barrier(0);
    __builtin_amdgcn_s_barrier();
    __builtin_amdgcn_sched_barrier(0);
    stB(1, 0); stB(1, 1);            // vm outstanding = 4 (steady entering-ph0 state)
    rdA(aqE, Ab0, 0);
    rdB(Bb0);

#pragma unroll 1
    for (int i = 0; i < 36; ++i) {
        const int T = 2 * i;
        // ph0: reads | barrier | stages (post-barrier!) | MFMA
        rdA(aqO, Ab0, 1);
        FB_L4;
        stA(T + 1, 0); stA(T + 1, 1); stB(T + 2, 0); stB(T + 2, 1);
        MFMA16(0, aqE);
        // ph1 (no barrier)
        rdA(aqE, Ab0, 2); FN_L4; MFMA16(1, aqO);
        // ph2 (no barrier)
        rdA(aqO, Ab0, 3); FN_L4; MFMA16(2, aqE);
        // ph3: vm(4) drains A(T+1)+B(T+1) stages; barrier; then cross-wave reads
        FB_V4L0;
        rdA(aqE, Ab1, 0);
        MFMA16(3, aqO);
        rdB(Bb1);                    // B(T+1) refill after last use of bq
        // ph4
        rdA(aqO, Ab1, 1);
        FB_L4;
        stA(T + 2, 0); stA(T + 2, 1); stB(T + 3, 0); stB(T + 3, 1);
        MFMA16(0, aqE);
        // ph5 (no barrier)
        rdA(aqE, Ab1, 2); FN_L4; MFMA16(1, aqO);
        // ph6 (no barrier)
        rdA(aqO, Ab1, 3); FN_L4; MFMA16(2, aqE);
        // ph7: vm(4) drains B(T+2)+A(T+2) stages; barrier; cross-wave reads
        FB_V4L0;
        rdA(aqE, Ab0, 0);
        MFMA16(3, aqO);
        rdB(Bb0);                    // B(T+2) refill
    }

    asm volatile("s_waitcnt vmcnt(0) lgkmcnt(0)" ::: "memory");

    // epilogue: D[(l>>4)*4+r][l&15] per 16x16 fragment
#pragma unroll
    for (int mi = 0; mi < 8; ++mi) {
#pragma unroll
        for (int ni = 0; ni < 4; ++ni) {
#pragma unroll
            for (int r = 0; r < 4; ++r) {
                int m = mt * 256 + wm + mi * 16 + (l >> 4) * 4 + r;
                int co = nt * 256 + wn + ni * 16 + (l & 15);
                out[(((size_t)(b * 4096 + m)) << 9) + co] = acc[mi][ni][r];
            }
        }
    }
#undef MFMA16
#undef FB_L4
#undef FB_V4L0
#undef FN_L4
}

// ---------------- launch ----------------

extern "C" void kernel_launch(void* const* d_in, const int* in_sizes, int n_in,
                              void* d_out, int out_size, void* d_ws, size_t ws_size,
                              hipStream_t stream) {
    const float* x = (const float*)d_in[0];
    const float* style = (const float*)d_in[1];
    const float* kern = (const float*)d_in[2];
    float* out = (float*)d_out;

    char* ws = (char*)d_ws;
    ushort* xpad = (ushort*)ws;                                // 35,684,352 B
    ushort* wT = (ushort*)(ws + 35684352);                     // 37,748,736 B
    float* Q = (float*)(ws + 35684352 + 37748736);             // 1,048,576 B
    float* sig = (float*)(ws + 35684352 + 37748736 + 1048576); // 16,384 B

    (void)hipFuncSetAttribute((const void*)conv_mfma,
                              hipFuncAttributeMaxDynamicSharedMemorySize, 131072);

    k_prep<<<9736, 256, 0, stream>>>(kern, Q, x, xpad);
    k_sigma<<<dim3(8, 8), 256, 0, stream>>>(style, Q, sig);
    k_wt<<<dim3(64, 9), 256, 0, stream>>>(kern, style, sig, wT);
    conv_mfma<<<256, 512, 131072, stream>>>(xpad, wT, out);
}

// Round 15
// 149.831 us; speedup vs baseline: 1.0697x; 1.0697x over previous
//
#include <hip/hip_runtime.h>

typedef __bf16 bf16x8 __attribute__((ext_vector_type(8)));
typedef float f32x4 __attribute__((ext_vector_type(4)));

#define SCALE_F 0.014731391274719738f   /* 1/sqrt(9*512) */
#define SCALE2_F 2.170138888888889e-4f  /* 1/4608 */

__device__ __forceinline__ ushort f2bf(float f) {
    uint x = __float_as_uint(f);
    uint r = (x + 0x7fffu + ((x >> 16) & 1u)) >> 16;
    return (ushort)r;
}

__device__ __forceinline__ void async_cp16(const void* g, void* l) {
    __builtin_amdgcn_global_load_lds(
        (const __attribute__((address_space(1))) void*)g,
        (__attribute__((address_space(3))) void*)l, 16, 0, 0);
}

// ---------------- fused prep ----------------
// blocks [0,1024): Q = scale^2 * sum_tap kern^2
// blocks [1024,9736): xpad = bf16(x * style)   (style folded into A)
// blocks [9736,10312): wTs = bf16(scale * kern) transposed to [tap][co][ci]
__global__ void k_prep(const float* __restrict__ kern, float* __restrict__ Q,
                       const float* __restrict__ x, const float* __restrict__ style,
                       ushort* __restrict__ xp, ushort* __restrict__ wTs) {
    int bx = blockIdx.x;
    int t = threadIdx.x;
    if (bx < 1024) {
        int idx = bx * 256 + t;
        float s = 0.f;
#pragma unroll
        for (int tp = 0; tp < 9; ++tp) { float v = kern[tp * 262144 + idx]; s += v * v; }
        Q[idx] = s * SCALE2_F;
        return;
    }
    if (bx < 9736) {
        int idx = (bx - 1024) * 256 + t;
        int pos = idx >> 6, e = idx & 63;
        int b = pos / 4356, rem = pos - b * 4356;
        int hp = rem / 66, wp = rem - hp * 66;
        int ci0 = e << 3;
        uint4 o = make_uint4(0u, 0u, 0u, 0u);
        if (hp >= 1 && hp <= 64 && wp >= 1 && wp <= 64) {
            const float4* s =
                (const float4*)(x + (((size_t)(b * 4096 + (hp - 1) * 64 + (wp - 1))) << 9) + ci0);
            const float4* st = (const float4*)(style + b * 512 + ci0);
            float4 v0 = s[0], v1 = s[1];
            float4 s0 = st[0], s1 = st[1];
            o.x = (uint)f2bf(v0.x * s0.x) | ((uint)f2bf(v0.y * s0.y) << 16);
            o.y = (uint)f2bf(v0.z * s0.z) | ((uint)f2bf(v0.w * s0.w) << 16);
            o.z = (uint)f2bf(v1.x * s1.x) | ((uint)f2bf(v1.y * s1.y) << 16);
            o.w = (uint)f2bf(v1.z * s1.z) | ((uint)f2bf(v1.w * s1.w) << 16);
        }
        *(uint4*)(xp + (((size_t)pos) << 9) + ci0) = o;
        return;
    }
    // wTs: transpose 64x64 tile of scale*kern (ci-major -> [tap][co][ci])
    __shared__ float tile[64][65];
    int wbx = bx - 9736;               // 0..575
    int tap = wbx >> 6;                // /64
    int r64 = wbx & 63;
    int ci0 = (r64 >> 3) << 6, co0 = (r64 & 7) << 6;
    int col = t & 63, rq = t >> 6;
#pragma unroll
    for (int r = 0; r < 16; ++r) {
        int ci_l = r * 4 + rq;
        tile[ci_l][col] = SCALE_F * kern[(size_t)(tap * 512 + ci0 + ci_l) * 512 + co0 + col];
    }
    __syncthreads();
#pragma unroll
    for (int r = 0; r < 4; ++r) {
        int q = r * 256 + t;
        int co_l = q >> 4;              // uniform per 16 lanes
        int ciq = (q & 15) << 2;        // lane-consecutive -> 128B contiguous writes
        float v0 = tile[ciq + 0][co_l];
        float v1 = tile[ciq + 1][co_l];
        float v2 = tile[ciq + 2][co_l];
        float v3 = tile[ciq + 3][co_l];
        uint lo = (uint)f2bf(v0) | ((uint)f2bf(v1) << 16);
        uint hi = (uint)f2bf(v2) | ((uint)f2bf(v3) << 16);
        *(uint2*)(&wTs[((size_t)(tap * 512 + co0 + co_l)) * 512 + ci0 + ciq]) =
            make_uint2(lo, hi);
    }
}

__global__ void k_sigma(const float* __restrict__ style, const float* __restrict__ Q,
                        float* __restrict__ sig) {
    __shared__ float s2[512];
    int b = blockIdx.x, cq = blockIdx.y;
    int t = threadIdx.x;
    {
        float s0 = style[b * 512 + t];
        float s1 = style[b * 512 + 256 + t];
        s2[t] = s0 * s0;
        s2[256 + t] = s1 * s1;
    }
    __syncthreads();
    int co = cq * 64 + (t & 63);
    int ciq = (t >> 6) * 128;
    float acc = 0.f;
#pragma unroll 16
    for (int ci = 0; ci < 128; ++ci) acc += s2[ciq + ci] * Q[(ciq + ci) * 512 + co];
    __shared__ float part[4][64];
    part[t >> 6][t & 63] = acc;
    __syncthreads();
    if (t < 64) {
        float v = part[0][t] + part[1][t] + part[2][t] + part[3][t];
        sig[b * 512 + cq * 64 + t] = rsqrtf(v + 1e-8f);
    }
}

// ---------------- main conv: R9 schedule verbatim; B batch-free; sigma in epilogue ----------------
__global__ __launch_bounds__(512, 2) void conv_mfma(const ushort* __restrict__ xpad,
                                                    const ushort* __restrict__ wTs,
                                                    const float* __restrict__ sig,
                                                    float* __restrict__ out) {
    extern __shared__ char lds[];

    const int wg = blockIdx.x;                      // 0..255
    const int swz = (wg & 7) * 32 + (wg >> 3);      // bijective XCD swizzle
    const int mt = swz & 15;
    const int nt = (swz >> 4) & 1;
    const int b = swz >> 5;

    const int tid = threadIdx.x;
    const int l = tid & 63, wv = tid >> 6;
    const int wm = (wv >> 2) * 128;
    const int wn = (wv & 3) * 64;
    const int ha = wv >> 2;          // A half this wave reads
    const int hb = (wv & 3) >> 1;    // B half this wave reads

    const int rl = l >> 3;
    const int g = (l & 7) ^ rl;      // data chunk pre-swizzle
    const ushort* baseA[2][2];
    const ushort* baseB[2][2];
#pragma unroll
    for (int h = 0; h < 2; ++h)
#pragma unroll
        for (int i = 0; i < 2; ++i) {
            int rloc = wv * 16 + i * 8 + rl;
            int R = h * 128 + rloc;
            baseA[h][i] = xpad + ((size_t)((b * 66 + mt * 4 + (R >> 6)) * 66 + (R & 63))) * 512 + g * 8;
            baseB[h][i] = wTs + ((size_t)(nt * 256 + R)) * 512 + g * 8;   // no batch term
        }
    const int so0 = (wv * 16) * 128;
    const int so1 = (wv * 16 + 8) * 128;

    auto offA = [](int t) -> int {
        int tap = t >> 3;
        int ky = (tap * 11) >> 5;
        int kx = tap - ky * 3;
        return (ky * 66 + kx) * 512 + ((t & 7) << 6);
    };
    auto offB = [](int t) -> int { return (t >> 3) * 262144 + ((t & 7) << 6); };

    auto stA = [&](int t, int h) {
        int ts = t > 71 ? 71 : t;
        int o = offA(ts);
        char* d = lds + (t & 1) * 32768 + h * 16384;
        async_cp16(baseA[h][0] + o, d + so0);
        async_cp16(baseA[h][1] + o, d + so1);
    };
    auto stB = [&](int t, int h) {
        int ts = t > 71 ? 71 : t;
        int o = offB(ts);
        char* d = lds + 65536 + (t & 1) * 32768 + h * 16384;
        async_cp16(baseB[h][0] + o, d + so0);
        async_cp16(baseB[h][1] + o, d + so1);
    };

    const int frow = l & 15;
    const int fchunk_base = l >> 4;   // 0..3
    const int fxor = l & 7;

    f32x4 acc[8][4];
#pragma unroll
    for (int mi = 0; mi < 8; ++mi)
#pragma unroll
        for (int ni = 0; ni < 4; ++ni) acc[mi][ni] = (f32x4){0.f, 0.f, 0.f, 0.f};

    bf16x8 bq[4][2];             // single bank, refilled post-MFMA at ph3/ph7
    bf16x8 aqE[2][2], aqO[2][2]; // A-frag parity banks (read 1 phase ahead)

    auto rdB = [&](const char* bB) {
#pragma unroll
        for (int kk = 0; kk < 2; ++kk)
#pragma unroll
            for (int ni = 0; ni < 4; ++ni) {
                int r = (wn & 64) + ni * 16 + frow;
                bq[ni][kk] = *(const bf16x8*)(bB + r * 128 +
                                              (((kk * 4 + fchunk_base) ^ fxor) * 16));
            }
    };
    auto rdA = [&](bf16x8 (&aq)[2][2], const char* aB, int q) {
#pragma unroll
        for (int m2 = 0; m2 < 2; ++m2)
#pragma unroll
            for (int kk = 0; kk < 2; ++kk) {
                int r = (2 * q + m2) * 16 + frow;
                aq[m2][kk] = *(const bf16x8*)(aB + r * 128 +
                                              (((kk * 4 + fchunk_base) ^ fxor) * 16));
            }
    };

#define FENCE_L4                                                        \
    {                                                                   \
        __builtin_amdgcn_sched_barrier(0);                              \
        asm volatile("s_waitcnt lgkmcnt(4)" ::: "memory");              \
        __builtin_amdgcn_s_barrier();                                   \
        __builtin_amdgcn_sched_barrier(0);                              \
    }
#define FENCE_L12                                                       \
    {                                                                   \
        __builtin_amdgcn_sched_barrier(0);                              \
        asm volatile("s_waitcnt lgkmcnt(12)" ::: "memory");             \
        __builtin_amdgcn_s_barrier();                                   \
        __builtin_amdgcn_sched_barrier(0);                              \
    }
#define FENCE_V4L4                                                      \
    {                                                                   \
        __builtin_amdgcn_sched_barrier(0);                              \
        asm volatile("s_waitcnt vmcnt(4) lgkmcnt(4)" ::: "memory");     \
        __builtin_amdgcn_s_barrier();                                   \
        __builtin_amdgcn_sched_barrier(0);                              \
    }
#define FENCE_V2L4                                                      \
    {                                                                   \
        __builtin_amdgcn_sched_barrier(0);                              \
        asm volatile("s_waitcnt vmcnt(2) lgkmcnt(4)" ::: "memory");     \
        __builtin_amdgcn_s_barrier();                                   \
        __builtin_amdgcn_sched_barrier(0);                              \
    }

#define MFMA16(Q, AQ)                                                                  \
    do {                                                                               \
        __builtin_amdgcn_s_setprio(1);                                                 \
        _Pragma("unroll") for (int kk = 0; kk < 2; ++kk)                               \
            _Pragma("unroll") for (int ni = 0; ni < 4; ++ni)                           \
                _Pragma("unroll") for (int m2 = 0; m2 < 2; ++m2)                       \
                    acc[2 * (Q) + m2][ni] = __builtin_amdgcn_mfma_f32_16x16x32_bf16(   \
                        (AQ)[m2][kk], bq[ni][kk], acc[2 * (Q) + m2][ni], 0, 0, 0);     \
        __builtin_amdgcn_s_setprio(0);                                                 \
    } while (0)

    const char* Ab0 = lds + ha * 16384;
    const char* Ab1 = lds + 32768 + ha * 16384;
    const char* Bb0 = lds + 65536 + hb * 16384;
    const char* Bb1 = lds + 98304 + hb * 16384;

    // prologue: land A(0),B(0); put B(1) in flight (vm=4); pre-read A(0)q0 + B(0)
    stA(0, 0); stA(0, 1);
    stB(0, 0); stB(0, 1);
    asm volatile("s_waitcnt vmcnt(0)" ::: "memory");
    __builtin_amdgcn_sched_barrier(0);
    __builtin_amdgcn_s_barrier();
    __builtin_amdgcn_sched_barrier(0);
    stB(1, 0); stB(1, 1);            // outstanding vm = 4 (= steady entering-ph0 state)
    rdA(aqE, Ab0, 0);                // A(0)q0   (lgkm: 4 older)
    rdB(Bb0);                        // B(0)     (lgkm: 8 younger)  -> 12 total

#pragma unroll 1
    for (int i = 0; i < 36; ++i) {
        const int T = 2 * i;
        // ph0
        rdA(aqO, Ab0, 1); stA(T + 1, 0);
        FENCE_L12; MFMA16(0, aqE);
        // ph1  (vm(4): drains B(T+1) for ph3's refill read)
        rdA(aqE, Ab0, 2); stA(T + 1, 1);
        FENCE_V4L4; MFMA16(1, aqO);
        // ph2  (vm(2): drains A(T+1) for ph3's aq read)
        rdA(aqO, Ab0, 3); stB(T + 2, 0);
        FENCE_V2L4; MFMA16(2, aqE);
        // ph3  (+ bq refill with B(T+1) after its last use)
        rdA(aqE, Ab1, 0); stB(T + 2, 1);
        FENCE_L4; MFMA16(3, aqO);
        rdB(Bb1);
        // ph4
        rdA(aqO, Ab1, 1); stA(T + 2, 0);
        FENCE_L12; MFMA16(0, aqE);
        // ph5
        rdA(aqE, Ab1, 2); stA(T + 2, 1);
        FENCE_L4; MFMA16(1, aqO);
        // ph6  (vm(2): drains B(T+2)+A(T+2) for ph7's reads)
        rdA(aqO, Ab1, 3); stB(T + 3, 0);
        FENCE_V2L4; MFMA16(2, aqE);
        // ph7  (+ bq refill with B(T+2); aq pre-read A(T+2)q0)
        rdA(aqE, Ab0, 0); stB(T + 3, 1);
        FENCE_L4; MFMA16(3, aqO);
        rdB(Bb0);
    }

    asm volatile("s_waitcnt vmcnt(0) lgkmcnt(0)" ::: "memory");

    // epilogue: demodulate (sigma per-co, exact f32) and store
    float sg[4];
#pragma unroll
    for (int ni = 0; ni < 4; ++ni)
        sg[ni] = sig[b * 512 + nt * 256 + wn + ni * 16 + (l & 15)];
#pragma unroll
    for (int mi = 0; mi < 8; ++mi) {
#pragma unroll
        for (int ni = 0; ni < 4; ++ni) {
#pragma unroll
            for (int r = 0; r < 4; ++r) {
                int m = mt * 256 + wm + mi * 16 + (l >> 4) * 4 + r;
                int co = nt * 256 + wn + ni * 16 + (l & 15);
                out[(((size_t)(b * 4096 + m)) << 9) + co] = acc[mi][ni][r] * sg[ni];
            }
        }
    }
#undef MFMA16
#undef FENCE_L4
#undef FENCE_L12
#undef FENCE_V4L4
#undef FENCE_V2L4
}

// ---------------- launch ----------------

extern "C" void kernel_launch(void* const* d_in, const int* in_sizes, int n_in,
                              void* d_out, int out_size, void* d_ws, size_t ws_size,
                              hipStream_t stream) {
    const float* x = (const float*)d_in[0];
    const float* style = (const float*)d_in[1];
    const float* kern = (const float*)d_in[2];
    float* out = (float*)d_out;

    char* ws = (char*)d_ws;
    ushort* xpad = (ushort*)ws;                                // 35,684,352 B
    ushort* wTs = (ushort*)(ws + 35684352);                    // 4,718,592 B
    float* Q = (float*)(ws + 35684352 + 4718592);              // 1,048,576 B
    float* sig = (float*)(ws + 35684352 + 4718592 + 1048576);  // 16,384 B

    (void)hipFuncSetAttribute((const void*)conv_mfma,
                              hipFuncAttributeMaxDynamicSharedMemorySize, 131072);

    k_prep<<<10312, 256, 0, stream>>>(kern, Q, x, style, xpad, wTs);
    k_sigma<<<dim3(8, 8), 256, 0, stream>>>(style, Q, sig);
    conv_mfma<<<256, 512, 131072, stream>>>(xpad, wTs, sig, out);
}